// Round 1
// baseline (108.312 us; speedup 1.0000x reference)
//
#include <hip/hip_runtime.h>

// GRU encoder, MI355X. Structure:
//  kernel 1: G[v][g] = b_ih[g] + (g<256 ? b_hh[g] : 0) + sum_e embed[v][e]*W_ih[g][e]
//            (input projection collapsed to a 1000x384 lookup table in d_ws; r/z hidden
//             biases folded in; n-gate bias must stay separate since r gates it)
//  kernel 2: persistent GRU. 256 blocks (1/CU) x 512 thr (8 waves), 32 batch rows/block.
//            W_hh bf16 B-fragments in VGPRs (weight-stationary), h state in f32 regs,
//            h re-quantized to bf16 each step into LDS in MFMA-A-fragment order with
//            XOR swizzle -> conflict-free ds_read_b128. xg gathered from L2-resident G
//            directly to registers, prefetched one step ahead.

typedef __bf16 bf16x8 __attribute__((ext_vector_type(8)));
typedef float  f32x4  __attribute__((ext_vector_type(4)));

#define NV   1000
#define EMB  64
#define HD   128
#define G3   384
#define SEQ  64
#define BB   32   // batch rows per block

__device__ __forceinline__ float sigm_f(float x) {
    return __builtin_amdgcn_rcpf(1.f + __builtin_amdgcn_exp2f(-1.44269504088896f * x));
}
__device__ __forceinline__ float tanh_f(float x) {
    // 1 - 2/(exp(2x)+1); saturates correctly at +-inf
    return 1.f - 2.f * __builtin_amdgcn_rcpf(1.f + __builtin_amdgcn_exp2f(2.88539008177793f * x));
}

__global__ void g_table_kernel(const float* __restrict__ embed,
                               const float* __restrict__ W_ih,
                               const float* __restrict__ b_ih,
                               const float* __restrict__ b_hh,
                               float* __restrict__ Gt)
{
    __shared__ float emb[EMB];
    const int v = blockIdx.x;
    const int g = threadIdx.x;              // 0..383
    if (g < EMB) emb[g] = embed[v * EMB + g];
    __syncthreads();
    const float* wr = W_ih + g * EMB;
    float s = b_ih[g] + (g < 2 * HD ? b_hh[g] : 0.f);   // fold b_hh for r,z gates only
    #pragma unroll
    for (int e = 0; e < EMB; e += 4) {
        const float4 w4 = *(const float4*)(wr + e);
        s += w4.x * emb[e] + w4.y * emb[e + 1] + w4.z * emb[e + 2] + w4.w * emb[e + 3];
    }
    Gt[v * G3 + g] = s;
}

// wave (cw,rw): cw in 0..3 column team (32 hid cols x 3 gates), rw in 0..1 (16 rows)
__global__ __launch_bounds__(512, 2) void gru_kernel(
    const int*   __restrict__ x,    const float* __restrict__ Gt,
    const float* __restrict__ Whh,  const float* __restrict__ bhh,
    const float* __restrict__ Wout, const float* __restrict__ bout,
    float* __restrict__ out)
{
    __shared__ unsigned short hA[BB * HD];  // bf16 h, fragment-permuted + XOR-swizzled
    __shared__ int xl[BB * SEQ];

    const int tid  = threadIdx.x;
    const int lane = tid & 63;
    const int wid  = tid >> 6;      // 0..7
    const int cw   = wid & 3;
    const int rw   = wid >> 2;
    const int c16  = lane & 15;
    const int quad = lane >> 4;
    const int br0  = blockIdx.x * BB;

    // ---- stage token indices (coalesced)
    #pragma unroll
    for (int i = 0; i < (BB * SEQ) / 512; ++i)
        xl[tid + i * 512] = x[br0 * SEQ + tid + i * 512];

    // ---- zero hA (h0 = 0)
    #pragma unroll
    for (int i = 0; i < (BB * HD) / (512 * 2); ++i)
        ((unsigned int*)hA)[tid + i * 512] = 0u;

    // ---- W_hh B-fragments -> registers (bf16 single precision)
    // frag elem j <-> k = ks*32 + quad*4 + (j&3) + 16*(j>>2); col = gate*128 + cw*32 + ht*16 + c16
    bf16x8 wf[3][2][4];
    #pragma unroll
    for (int gate = 0; gate < 3; ++gate)
    #pragma unroll
    for (int ht = 0; ht < 2; ++ht)
    #pragma unroll
    for (int ks = 0; ks < 4; ++ks) {
        const int col = gate * HD + cw * 32 + ht * 16 + c16;
        const float* p = Whh + col * HD + ks * 32 + quad * 4;
        const float4 a = *(const float4*)p;
        const float4 b = *(const float4*)(p + 16);
        bf16x8 f;
        f[0] = (__bf16)a.x; f[1] = (__bf16)a.y; f[2] = (__bf16)a.z; f[3] = (__bf16)a.w;
        f[4] = (__bf16)b.x; f[5] = (__bf16)b.y; f[6] = (__bf16)b.z; f[7] = (__bf16)b.w;
        wf[gate][ht][ks] = f;
    }
    // ---- W_out B-fragments
    bf16x8 wo[2][4];
    #pragma unroll
    for (int ht = 0; ht < 2; ++ht)
    #pragma unroll
    for (int ks = 0; ks < 4; ++ks) {
        const int col = cw * 32 + ht * 16 + c16;
        const float* p = Wout + col * HD + ks * 32 + quad * 4;
        const float4 a = *(const float4*)p;
        const float4 b = *(const float4*)(p + 16);
        bf16x8 f;
        f[0] = (__bf16)a.x; f[1] = (__bf16)a.y; f[2] = (__bf16)a.z; f[3] = (__bf16)a.w;
        f[4] = (__bf16)b.x; f[5] = (__bf16)b.y; f[6] = (__bf16)b.z; f[7] = (__bf16)b.w;
        wo[ht][ks] = f;
    }

    const float bn0 = bhh[2 * HD + cw * 32 + c16];        // n-gate bias (NOT folded)
    const float bn1 = bhh[2 * HD + cw * 32 + 16 + c16];
    const float bo0 = bout[cw * 32 + c16];
    const float bo1 = bout[cw * 32 + 16 + c16];

    float hreg[2][4] = {{0.f,0.f,0.f,0.f},{0.f,0.f,0.f,0.f}};  // [ht][j], f32 master state

    __syncthreads();   // xl + hA zeros visible

    // ---- prefetch xg for t=0 (direct from L2-resident G table)
    float pf[3][2][4];
    {
        int tok[4];
        #pragma unroll
        for (int j = 0; j < 4; ++j)
            tok[j] = xl[(rw * 16 + quad * 4 + j) * SEQ + 0];
        #pragma unroll
        for (int j = 0; j < 4; ++j) {
            const float* gp = Gt + tok[j] * G3 + cw * 32 + c16;
            #pragma unroll
            for (int gate = 0; gate < 3; ++gate) {
                pf[gate][0][j] = gp[gate * HD];
                pf[gate][1][j] = gp[gate * HD + 16];
            }
        }
    }

    const f32x4 z4 = {0.f, 0.f, 0.f, 0.f};

    for (int t = 0; t < SEQ; ++t) {
        // ---- MFMA: hg = bf16(h_{t-1}) @ W_hh^T (wave's 96 gate-cols x its 16 rows)
        f32x4 acc[3][2];
        #pragma unroll
        for (int g2 = 0; g2 < 3; ++g2) { acc[g2][0] = z4; acc[g2][1] = z4; }
        #pragma unroll
        for (int ks = 0; ks < 4; ++ks) {
            const int arow = rw * 16 + c16;
            const int aoff = arow * 256 + ((ks * 64 + quad * 16) ^ ((arow & 7) << 4));
            const bf16x8 af = *(const bf16x8*)((const char*)hA + aoff);
            #pragma unroll
            for (int gate = 0; gate < 3; ++gate)
            #pragma unroll
            for (int ht = 0; ht < 2; ++ht)
                acc[gate][ht] = __builtin_amdgcn_mfma_f32_16x16x32_bf16(
                    af, wf[gate][ht][ks], acc[gate][ht], 0, 0, 0);
        }

        // ---- pointwise GRU cell (all f32; acc elem j -> row rw*16+quad*4+j, col hid)
        unsigned short hbits[2][4];
        #pragma unroll
        for (int ht = 0; ht < 2; ++ht) {
            const float bn_ = ht ? bn1 : bn0;
            #pragma unroll
            for (int j = 0; j < 4; ++j) {
                const float r  = sigm_f(pf[0][ht][j] + acc[0][ht][j]);
                const float zg = sigm_f(pf[1][ht][j] + acc[1][ht][j]);
                const float n  = tanh_f(pf[2][ht][j] + r * (acc[2][ht][j] + bn_));
                const float hp = hreg[ht][j];
                const float hn = zg * (hp - n) + n;
                hreg[ht][j] = hn;
                hbits[ht][j] = __builtin_bit_cast(unsigned short, (__bf16)hn);
            }
        }

        // ---- prefetch xg for t+1 (issued now; consumed next iteration after ~1 step)
        if (t + 1 < SEQ) {
            int tok[4];
            #pragma unroll
            for (int j = 0; j < 4; ++j)
                tok[j] = xl[(rw * 16 + quad * 4 + j) * SEQ + t + 1];
            #pragma unroll
            for (int j = 0; j < 4; ++j) {
                const float* gp = Gt + tok[j] * G3 + cw * 32 + c16;
                #pragma unroll
                for (int gate = 0; gate < 3; ++gate) {
                    pf[gate][0][j] = gp[gate * HD];
                    pf[gate][1][j] = gp[gate * HD + 16];
                }
            }
        }

        __syncthreads();   // A: all hA fragment reads of this step complete

        // ---- write h_t to hA (fragment-permuted index + same XOR swizzle)
        #pragma unroll
        for (int ht = 0; ht < 2; ++ht) {
            const int hid  = cw * 32 + ht * 16 + c16;
            const int sidx = ((hid >> 5) << 5) + (((hid & 15) >> 2) << 3)
                           + (((hid >> 4) & 1) << 2) + (hid & 3);
            #pragma unroll
            for (int j = 0; j < 4; ++j) {
                const int row = rw * 16 + quad * 4 + j;
                const int off = row * 256 + ((sidx * 2) ^ ((row & 7) << 4));
                *(unsigned short*)((char*)hA + off) = hbits[ht][j];
            }
        }
        __syncthreads();   // B: h_t visible to all waves
    }

    // ---- epilogue: out = h_final @ W_out^T + b_out
    f32x4 oacc[2] = {z4, z4};
    #pragma unroll
    for (int ks = 0; ks < 4; ++ks) {
        const int arow = rw * 16 + c16;
        const int aoff = arow * 256 + ((ks * 64 + quad * 16) ^ ((arow & 7) << 4));
        const bf16x8 af = *(const bf16x8*)((const char*)hA + aoff);
        #pragma unroll
        for (int ht = 0; ht < 2; ++ht)
            oacc[ht] = __builtin_amdgcn_mfma_f32_16x16x32_bf16(af, wo[ht][ks], oacc[ht], 0, 0, 0);
    }
    #pragma unroll
    for (int ht = 0; ht < 2; ++ht) {
        const float bo_ = ht ? bo1 : bo0;
        #pragma unroll
        for (int j = 0; j < 4; ++j) {
            const int row = br0 + rw * 16 + quad * 4 + j;
            out[row * HD + cw * 32 + ht * 16 + c16] = oacc[ht][j] + bo_;
        }
    }
}

extern "C" void kernel_launch(void* const* d_in, const int* in_sizes, int n_in,
                              void* d_out, int out_size, void* d_ws, size_t ws_size,
                              hipStream_t stream) {
    const int*   x     = (const int*)  d_in[0];
    const float* embed = (const float*)d_in[1];
    const float* W_ih  = (const float*)d_in[2];
    const float* W_hh  = (const float*)d_in[3];
    const float* b_ih  = (const float*)d_in[4];
    const float* b_hh  = (const float*)d_in[5];
    const float* W_out = (const float*)d_in[6];
    const float* b_out = (const float*)d_in[7];
    float* outp = (float*)d_out;
    float* Gt   = (float*)d_ws;                 // 1000*384*4 = 1.536 MB scratch

    const int Bsz = in_sizes[0] / SEQ;          // 8192

    g_table_kernel<<<NV, G3, 0, stream>>>(embed, W_ih, b_ih, b_hh, Gt);
    gru_kernel<<<Bsz / BB, 512, 0, stream>>>(x, Gt, W_hh, b_hh, W_out, b_out, outp);
}